// Round 4
// baseline (364.269 us; speedup 1.0000x reference)
//
#include <hip/hip_runtime.h>
#include <math.h>

#define NN 50000
#define NE 800000
#define CH 64

typedef float v4f __attribute__((ext_vector_type(4)));

// ---------------- counting-sort pipeline (atomic-free aggregation) ----------

// 1) histogram of dst
__global__ __launch_bounds__(256) void hist_k(const int* __restrict__ ei,
                                              int* __restrict__ count) {
    int i = blockIdx.x * 256 + threadIdx.x;
    const int stride = gridDim.x * 256;
    for (int e = i; e < NE; e += stride)
        atomicAdd(&count[ei[NE + e]], 1);
}

// 2) exclusive prefix sum over count[0..NN) -> start[0..NN], cursor copy
__global__ __launch_bounds__(1024) void scan_k(const int* __restrict__ count,
                                               int* __restrict__ start,
                                               int* __restrict__ cursor) {
    __shared__ int part[1024];
    const int t = threadIdx.x;
    const int per = (NN + 1023) / 1024;  // 49
    const int lo = t * per;
    const int hi = (lo + per < NN) ? lo + per : NN;
    int sum = 0;
    for (int i = lo; i < hi; ++i) sum += count[i];
    part[t] = sum;
    __syncthreads();
    for (int off = 1; off < 1024; off <<= 1) {
        int add = (t >= off) ? part[t - off] : 0;
        __syncthreads();
        part[t] += add;
        __syncthreads();
    }
    int run = part[t] - sum;  // exclusive base for this thread's range
    for (int i = lo; i < hi; ++i) {
        start[i] = run;
        cursor[i] = run;
        run += count[i];
    }
    if (t == 1023) start[NN] = run;  // == NE
}

// 3) place (src, norm) into dst-sorted order
__global__ __launch_bounds__(256) void place_k(const int* __restrict__ ei,
                                               const float* __restrict__ ea,
                                               int* __restrict__ cursor,
                                               int* __restrict__ ssrc,
                                               float* __restrict__ snrm) {
    int i = blockIdx.x * 256 + threadIdx.x;
    const int stride = gridDim.x * 256;
    for (int e = i; e < NE; e += stride) {
        const int src = ei[e];
        const int dst = ei[NE + e];
        const float a0 = ea[3 * e + 0];
        const float a1 = ea[3 * e + 1];
        const float a2 = ea[3 * e + 2];
        const float nrm = sqrtf(a0 * a0 + a1 * a1 + a2 * a2);
        const int pos = atomicAdd(&cursor[dst], 1);
        ssrc[pos] = src;
        snrm[pos] = nrm;
    }
}

// 4) per-node register accumulation: s[n,c] = sum_{e in seg(n)} nrm_e * x[src_e, c]
//    One wave per node, lane = channel. 4-deep unroll pipelines the random
//    x-row gathers (L2/L3 latency hiding). Zero atomics, one row-write per node.
__global__ __launch_bounds__(256) void agg_k(const float* __restrict__ x,
                                             const int* __restrict__ start,
                                             const int* __restrict__ ssrc,
                                             const float* __restrict__ snrm,
                                             float* __restrict__ s) {
    const int c = threadIdx.x & 63;
    int w = (int)((blockIdx.x * 256u + threadIdx.x) >> 6);
    const int nw = (int)((gridDim.x * 256u) >> 6);
    for (int n = w; n < NN; n += nw) {
        const int b = start[n];
        const int e = start[n + 1];
        float acc = 0.f;
        int j = b;
        for (; j + 4 <= e; j += 4) {
            const int i0 = ssrc[j], i1 = ssrc[j + 1], i2 = ssrc[j + 2], i3 = ssrc[j + 3];
            const float w0 = snrm[j], w1 = snrm[j + 1], w2 = snrm[j + 2], w3 = snrm[j + 3];
            const float x0 = x[(size_t)i0 * CH + c];
            const float x1 = x[(size_t)i1 * CH + c];
            const float x2 = x[(size_t)i2 * CH + c];
            const float x3 = x[(size_t)i3 * CH + c];
            acc = fmaf(w0, x0, acc);
            acc = fmaf(w1, x1, acc);
            acc = fmaf(w2, x2, acc);
            acc = fmaf(w3, x3, acc);
        }
        for (; j < e; ++j)
            acc = fmaf(snrm[j], x[(size_t)ssrc[j] * CH + c], acc);
        s[(size_t)n * CH + c] = acc;
    }
}

// ---------------- fallback scatter (round-2 proven, atomic-rate bound) ------
__global__ __launch_bounds__(256) void scatter_r2(const float* __restrict__ x,
                                                  const int* __restrict__ ei,
                                                  const float* __restrict__ ea,
                                                  float* s) {
    const int lane = threadIdx.x & 63;
    int w = (int)((blockIdx.x * 256u + threadIdx.x) >> 6);
    const int nw = (int)((gridDim.x * 256u) >> 6);
    for (int e = w; e < NE; e += nw) {
        const int src = ei[e];
        const int dst = ei[NE + e];
        const float a0 = ea[3 * e + 0];
        const float a1 = ea[3 * e + 1];
        const float a2 = ea[3 * e + 2];
        const float nrm = sqrtf(a0 * a0 + a1 * a1 + a2 * a2);
        atomicAdd(&s[(size_t)dst * CH + lane], nrm * x[(size_t)src * CH + lane]);
    }
}

// ---------------- epilogue: out[n,o] = x[n,:]·psi[o,:] + s[n,:]·phi[o,:] ----
// Weights-in-registers (128 VGPR/lane, fully static indexing). Row values are
// wave-uniform float4 broadcast loads -> pure VALU inner loop, no LDS.
// s may alias out: each row is read fully before its store, rows wave-exclusive.
__global__ __launch_bounds__(256) void out_k(const float* __restrict__ x,
                                             const float* s,
                                             const float* __restrict__ phi,
                                             const float* __restrict__ psi,
                                             float* out) {
    const int o = threadIdx.x & 63;
    const int wave = (int)((blockIdx.x * 256u + threadIdx.x) >> 6);
    const int nwave = (int)((gridDim.x * 256u) >> 6);

    float wpsi[CH], wphi[CH];
#pragma unroll
    for (int i4 = 0; i4 < 16; ++i4) {
        v4f a = *(const v4f*)(psi + (size_t)o * CH + 4 * i4);
        v4f b = *(const v4f*)(phi + (size_t)o * CH + 4 * i4);
        wpsi[4 * i4 + 0] = a.x; wpsi[4 * i4 + 1] = a.y;
        wpsi[4 * i4 + 2] = a.z; wpsi[4 * i4 + 3] = a.w;
        wphi[4 * i4 + 0] = b.x; wphi[4 * i4 + 1] = b.y;
        wphi[4 * i4 + 2] = b.z; wphi[4 * i4 + 3] = b.w;
    }

    for (int n = wave; n < NN; n += nwave) {
        const v4f* xp = (const v4f*)(x + (size_t)n * CH);
        const v4f* sp = (const v4f*)(s + (size_t)n * CH);
        float acc = 0.f;
#pragma unroll
        for (int i4 = 0; i4 < 16; ++i4) {
            v4f xv = xp[i4];
            v4f sv = sp[i4];
            acc = fmaf(xv.x, wpsi[4 * i4 + 0], acc);
            acc = fmaf(xv.y, wpsi[4 * i4 + 1], acc);
            acc = fmaf(xv.z, wpsi[4 * i4 + 2], acc);
            acc = fmaf(xv.w, wpsi[4 * i4 + 3], acc);
            acc = fmaf(sv.x, wphi[4 * i4 + 0], acc);
            acc = fmaf(sv.y, wphi[4 * i4 + 1], acc);
            acc = fmaf(sv.z, wphi[4 * i4 + 2], acc);
            acc = fmaf(sv.w, wphi[4 * i4 + 3], acc);
        }
        out[(size_t)n * CH + o] = acc;
    }
}

extern "C" void kernel_launch(void* const* d_in, const int* in_sizes, int n_in,
                              void* d_out, int out_size, void* d_ws, size_t ws_size,
                              hipStream_t stream) {
    const float* x   = (const float*)d_in[0];
    const int*   ei  = (const int*)d_in[1];
    const float* ea  = (const float*)d_in[2];
    const float* phi = (const float*)d_in[3];
    const float* psi = (const float*)d_in[4];
    float* out = (float*)d_out;

    // ws layout: count[NN] | start[NN+1] | cursor[NN] | ssrc[NE] | snrm[NE]
    const size_t need = ((size_t)NN + (NN + 1) + NN + NE) * sizeof(int) + (size_t)NE * sizeof(float);

    if (ws_size >= need) {
        int* count  = (int*)d_ws;
        int* start  = count + NN;
        int* cursor = start + (NN + 1);
        int* ssrc   = cursor + NN;
        float* snrm = (float*)(ssrc + NE);

        (void)hipMemsetAsync(count, 0, (size_t)NN * sizeof(int), stream);
        hist_k<<<1024, 256, 0, stream>>>(ei, count);
        scan_k<<<1, 1024, 0, stream>>>(count, start, cursor);
        place_k<<<1024, 256, 0, stream>>>(ei, ea, cursor, ssrc, snrm);
        agg_k<<<2048, 256, 0, stream>>>(x, start, ssrc, snrm, out);  // s lives in out
        out_k<<<512, 256, 0, stream>>>(x, out, phi, psi, out);
    } else {
        // fallback: proven round-2 path (atomic-rate bound)
        (void)hipMemsetAsync(out, 0, (size_t)NN * CH * sizeof(float), stream);
        scatter_r2<<<4096, 256, 0, stream>>>(x, ei, ea, out);
        out_k<<<512, 256, 0, stream>>>(x, out, phi, psi, out);
    }
}

// Round 5
// 265.434 us; speedup vs baseline: 1.3724x; 1.3724x over previous
//
#include <hip/hip_runtime.h>
#include <math.h>

#define NN 50000
#define NE 800000
#define CH 64
#define SCAN_BLK 1024
#define NB1 ((NN + SCAN_BLK - 1) / SCAN_BLK)  // 49

typedef float v4f __attribute__((ext_vector_type(4)));

// ---------------- counting-sort pipeline (atomic-free aggregation) ----------

// 1) histogram of dst
__global__ __launch_bounds__(256) void hist_k(const int* __restrict__ ei,
                                              int* __restrict__ count) {
    int i = blockIdx.x * 256 + threadIdx.x;
    const int stride = gridDim.x * 256;
    for (int e = i; e < NE; e += stride)
        atomicAdd(&count[ei[NE + e]], 1);
}

// 2a) per-block (1024-elem) local exclusive scan + block total
__global__ __launch_bounds__(256) void scan1_k(const int* __restrict__ count,
                                               int* __restrict__ start,
                                               int* __restrict__ blockSum) {
    __shared__ int lds[256];
    const int t = threadIdx.x;
    const int base = blockIdx.x * SCAN_BLK + t * 4;
    int c0 = 0, c1 = 0, c2 = 0, c3 = 0;
    if (base + 3 < NN) {
        int4 v = *(const int4*)(count + base);
        c0 = v.x; c1 = v.y; c2 = v.z; c3 = v.w;
    } else {
        if (base + 0 < NN) c0 = count[base + 0];
        if (base + 1 < NN) c1 = count[base + 1];
        if (base + 2 < NN) c2 = count[base + 2];
    }
    const int tsum = c0 + c1 + c2 + c3;
    lds[t] = tsum;
    __syncthreads();
    for (int off = 1; off < 256; off <<= 1) {
        int add = (t >= off) ? lds[t - off] : 0;
        __syncthreads();
        lds[t] += add;
        __syncthreads();
    }
    if (t == 255) blockSum[blockIdx.x] = lds[255];
    int r = lds[t] - tsum;  // thread-exclusive base within block
    if (base + 0 < NN) start[base + 0] = r; r += c0;
    if (base + 1 < NN) start[base + 1] = r; r += c1;
    if (base + 2 < NN) start[base + 2] = r; r += c2;
    if (base + 3 < NN) start[base + 3] = r;
}

// 2b) single-wave scan of the 49 block sums
__global__ __launch_bounds__(64) void scan2_k(const int* __restrict__ blockSum,
                                              int* __restrict__ blockOff,
                                              int* __restrict__ start) {
    const int t = threadIdx.x;
    const int orig = (t < NB1) ? blockSum[t] : 0;
    int v = orig;
    for (int off = 1; off < 64; off <<= 1) {
        int n = __shfl_up(v, off, 64);
        if (t >= off) v += n;
    }
    if (t < NB1) blockOff[t] = v - orig;   // exclusive
    if (t == NB1 - 1) start[NN] = v;       // total == NE
}

// 2c) add block offsets; materialize cursor
__global__ __launch_bounds__(256) void scan3_k(int* __restrict__ start,
                                               int* __restrict__ cursor,
                                               const int* __restrict__ blockOff) {
    const int t = threadIdx.x;
    const int base = blockIdx.x * SCAN_BLK + t * 4;
    const int off = blockOff[blockIdx.x];
    if (base + 3 < NN) {
        int4 v = *(const int4*)(start + base);
        v.x += off; v.y += off; v.z += off; v.w += off;
        *(int4*)(start + base) = v;
        *(int4*)(cursor + base) = v;
    } else {
        for (int k = 0; k < 4; ++k)
            if (base + k < NN) {
                int v = start[base + k] + off;
                start[base + k] = v;
                cursor[base + k] = v;
            }
    }
}

// 3) place packed (src, norm) into dst-sorted order — one 8B store per edge
__global__ __launch_bounds__(256) void place_k(const int* __restrict__ ei,
                                               const float* __restrict__ ea,
                                               int* __restrict__ cursor,
                                               int2* __restrict__ pp) {
    int i = blockIdx.x * 256 + threadIdx.x;
    const int stride = gridDim.x * 256;
    for (int e = i; e < NE; e += stride) {
        const int src = ei[e];
        const int dst = ei[NE + e];
        const float a0 = ea[3 * e + 0];
        const float a1 = ea[3 * e + 1];
        const float a2 = ea[3 * e + 2];
        const float nrm = sqrtf(a0 * a0 + a1 * a1 + a2 * a2);
        const int pos = atomicAdd(&cursor[dst], 1);
        int2 pr; pr.x = src; pr.y = __float_as_int(nrm);
        pp[pos] = pr;
    }
}

// 4) per-node register accumulation: s[n,c] = sum_{e in seg(n)} nrm_e * x[src_e, c]
//    One wave per node, lane = channel; 4-deep unrolled gathers. Zero f32 atomics.
__global__ __launch_bounds__(256) void agg_k(const float* __restrict__ x,
                                             const int* __restrict__ start,
                                             const int2* __restrict__ pp,
                                             float* __restrict__ s) {
    const int c = threadIdx.x & 63;
    int w = (int)((blockIdx.x * 256u + threadIdx.x) >> 6);
    const int nw = (int)((gridDim.x * 256u) >> 6);
    for (int n = w; n < NN; n += nw) {
        const int b = start[n];
        const int e = start[n + 1];
        float acc = 0.f;
        int j = b;
        for (; j + 4 <= e; j += 4) {
            const int2 p0 = pp[j], p1 = pp[j + 1], p2 = pp[j + 2], p3 = pp[j + 3];
            const float x0 = x[(size_t)p0.x * CH + c];
            const float x1 = x[(size_t)p1.x * CH + c];
            const float x2 = x[(size_t)p2.x * CH + c];
            const float x3 = x[(size_t)p3.x * CH + c];
            acc = fmaf(__int_as_float(p0.y), x0, acc);
            acc = fmaf(__int_as_float(p1.y), x1, acc);
            acc = fmaf(__int_as_float(p2.y), x2, acc);
            acc = fmaf(__int_as_float(p3.y), x3, acc);
        }
        for (; j < e; ++j) {
            const int2 p = pp[j];
            acc = fmaf(__int_as_float(p.y), x[(size_t)p.x * CH + c], acc);
        }
        s[(size_t)n * CH + c] = acc;
    }
}

// ---------------- fallback scatter (round-2 proven, atomic-rate bound) ------
__global__ __launch_bounds__(256) void scatter_r2(const float* __restrict__ x,
                                                  const int* __restrict__ ei,
                                                  const float* __restrict__ ea,
                                                  float* s) {
    const int lane = threadIdx.x & 63;
    int w = (int)((blockIdx.x * 256u + threadIdx.x) >> 6);
    const int nw = (int)((gridDim.x * 256u) >> 6);
    for (int e = w; e < NE; e += nw) {
        const int src = ei[e];
        const int dst = ei[NE + e];
        const float a0 = ea[3 * e + 0];
        const float a1 = ea[3 * e + 1];
        const float a2 = ea[3 * e + 2];
        const float nrm = sqrtf(a0 * a0 + a1 * a1 + a2 * a2);
        atomicAdd(&s[(size_t)dst * CH + lane], nrm * x[(size_t)src * CH + lane]);
    }
}

// ---------------- epilogue: out[n,o] = x[n,:]·psi[o,:] + s[n,:]·phi[o,:] ----
// Weights-in-registers (128 VGPR/lane, static indexing); wave-uniform float4
// row broadcasts; pure-VALU inner loop. s may alias out (row read-before-write,
// rows wave-exclusive -> race-free).
__global__ __launch_bounds__(256) void out_k(const float* __restrict__ x,
                                             const float* s,
                                             const float* __restrict__ phi,
                                             const float* __restrict__ psi,
                                             float* out) {
    const int o = threadIdx.x & 63;
    const int wave = (int)((blockIdx.x * 256u + threadIdx.x) >> 6);
    const int nwave = (int)((gridDim.x * 256u) >> 6);

    float wpsi[CH], wphi[CH];
#pragma unroll
    for (int i4 = 0; i4 < 16; ++i4) {
        v4f a = *(const v4f*)(psi + (size_t)o * CH + 4 * i4);
        v4f b = *(const v4f*)(phi + (size_t)o * CH + 4 * i4);
        wpsi[4 * i4 + 0] = a.x; wpsi[4 * i4 + 1] = a.y;
        wpsi[4 * i4 + 2] = a.z; wpsi[4 * i4 + 3] = a.w;
        wphi[4 * i4 + 0] = b.x; wphi[4 * i4 + 1] = b.y;
        wphi[4 * i4 + 2] = b.z; wphi[4 * i4 + 3] = b.w;
    }

    for (int n = wave; n < NN; n += nwave) {
        const v4f* xp = (const v4f*)(x + (size_t)n * CH);
        const v4f* sp = (const v4f*)(s + (size_t)n * CH);
        float acc = 0.f;
#pragma unroll
        for (int i4 = 0; i4 < 16; ++i4) {
            v4f xv = xp[i4];
            v4f sv = sp[i4];
            acc = fmaf(xv.x, wpsi[4 * i4 + 0], acc);
            acc = fmaf(xv.y, wpsi[4 * i4 + 1], acc);
            acc = fmaf(xv.z, wpsi[4 * i4 + 2], acc);
            acc = fmaf(xv.w, wpsi[4 * i4 + 3], acc);
            acc = fmaf(sv.x, wphi[4 * i4 + 0], acc);
            acc = fmaf(sv.y, wphi[4 * i4 + 1], acc);
            acc = fmaf(sv.z, wphi[4 * i4 + 2], acc);
            acc = fmaf(sv.w, wphi[4 * i4 + 3], acc);
        }
        out[(size_t)n * CH + o] = acc;
    }
}

extern "C" void kernel_launch(void* const* d_in, const int* in_sizes, int n_in,
                              void* d_out, int out_size, void* d_ws, size_t ws_size,
                              hipStream_t stream) {
    const float* x   = (const float*)d_in[0];
    const int*   ei  = (const int*)d_in[1];
    const float* ea  = (const float*)d_in[2];
    const float* phi = (const float*)d_in[3];
    const float* psi = (const float*)d_in[4];
    float* out = (float*)d_out;

    // ws layout (8B-aligned first): pair[NE] | count[NN] | start[NN+1] |
    //                               cursor[NN] | blockSum[64] | blockOff[64]
    const size_t need = (size_t)NE * 8 + ((size_t)NN + (NN + 1) + NN + 128) * 4;

    if (ws_size >= need) {
        int2* pp    = (int2*)d_ws;
        int* count  = (int*)(pp + NE);
        int* start  = count + NN;
        int* cursor = start + (NN + 1);
        int* blockSum = cursor + NN;
        int* blockOff = blockSum + 64;

        (void)hipMemsetAsync(count, 0, (size_t)NN * sizeof(int), stream);
        hist_k<<<1024, 256, 0, stream>>>(ei, count);
        scan1_k<<<NB1, 256, 0, stream>>>(count, start, blockSum);
        scan2_k<<<1, 64, 0, stream>>>(blockSum, blockOff, start);
        scan3_k<<<NB1, 256, 0, stream>>>(start, cursor, blockOff);
        place_k<<<1024, 256, 0, stream>>>(ei, ea, cursor, pp);
        agg_k<<<2048, 256, 0, stream>>>(x, start, pp, out);  // s lives in out
        out_k<<<512, 256, 0, stream>>>(x, out, phi, psi, out);
    } else {
        // fallback: proven round-2 path (atomic-rate bound)
        (void)hipMemsetAsync(out, 0, (size_t)NN * CH * sizeof(float), stream);
        scatter_r2<<<4096, 256, 0, stream>>>(x, ei, ea, out);
        out_k<<<512, 256, 0, stream>>>(x, out, phi, psi, out);
    }
}